// Round 8
// baseline (4007.711 us; speedup 1.0000x reference)
//
#include <hip/hip_runtime.h>
#include <math.h>

#define MR_C     256
#define MR_L     8192
#define MR_DEPTH 12
#define TPB      256
#define NG       (MR_L / 4)    // 2048 float4 groups per row

// R9 THEORY: unified spill model — HBM traffic tracks (register demand -
// budget) across ALL rounds (R1: 80-64 -> 9.3GB; R5: 190-128 -> 14.5GB;
// R6/R7: 270-256 -> 7GB; waves_per_eu(1,1) proved 256 is the ARCH ceiling,
// not a heuristic). Fix = reduce demand below 256: carry res in 8 NAMED
// float4 struct members (compile-time selection only), process groups in
// DESCENDING K so lower-K members still hold previous-level values ->
// own-run taps come from registers. LDS reads/level drop 32 -> <=24 (total
// 384 -> 210/thread), peak demand ~ 64 persistent + 96 landing + temps
// ~ 190 < 256 -> zero forced spill with margin.

__device__ __forceinline__ float4 f4z() { return make_float4(0.f, 0.f, 0.f, 0.f); }

struct Res8 { float4 r0, r1, r2, r3, r4, r5, r6, r7; };

template<int E>
__device__ __forceinline__ float4 rget(const Res8& r) {
    if constexpr      (E == 0) return r.r0;
    else if constexpr (E == 1) return r.r1;
    else if constexpr (E == 2) return r.r2;
    else if constexpr (E == 3) return r.r3;
    else if constexpr (E == 4) return r.r4;
    else if constexpr (E == 5) return r.r5;
    else if constexpr (E == 6) return r.r6;
    else                       return r.r7;
}
template<int E>
__device__ __forceinline__ void rset(Res8& r, const float4 v) {
    if constexpr      (E == 0) r.r0 = v;
    else if constexpr (E == 1) r.r1 = v;
    else if constexpr (E == 2) r.r2 = v;
    else if constexpr (E == 3) r.r3 = v;
    else if constexpr (E == 4) r.r4 = v;
    else if constexpr (E == 5) r.r5 = v;
    else if constexpr (E == 6) r.r6 = v;
    else                       r.r7 = v;
}

// LDS tap at own-run-relative group index E (E < 0: neighbor thread's group).
// Own groups of thread t are g = t*8+k at LDS slot (k<<8)+t (transposed layout:
// consecutive tid -> consecutive slots, conflict-free, tid + constant offsets).
template<int E>
__device__ __forceinline__ float4 lds_tap(const float4* __restrict__ bc, const int tid)
{
    constexpr int em = ((E % 8) + 8) % 8;   // true mod 8
    constexpr int ef = (E - em) / 8;        // floor div 8 (negative)
    return (tid + ef >= 0) ? bc[(em << 8) + tid + ef] : f4z();   // causal zero-pad
}

// Tap: registers when the value is in our own run (descending-K keeps members
// E<K old), LDS otherwise.
template<int E>
__device__ __forceinline__ float4 tap(const Res8& r, const float4* __restrict__ bc, const int tid)
{
    if constexpr (E >= 0) return rget<E>(r);
    else                  return lds_tap<E>(bc, tid);
}

// One group-step. acc is ONE named float4 by reference; res by struct ref with
// compile-time member access only.
// coefficient of x[t-d*j] is h[3-j]:  F.w*x[t] + F.z*x[t-d] + F.y*x[t-2d] + F.x*x[t-3d]
// G1 = wi*F1 pre-folded; at LEV==11, G1 = w1*F1 + w0*F0 (res_lo folded, no nl).
template<int LEV, int K>
__device__ __forceinline__ void gstep(
    Res8& r, float4& acc,
    const float4* __restrict__ bc, float4* __restrict__ bn,
    const int tid, const float4 F0, const float4 G1)
{
    constexpr int d = 1 << LEV;
    const float4 rl = rget<K>(r);
    float4 t1, t2, t3;   // taps at t-d, t-2d, t-3d

    if constexpr (d == 1) {
        const float4 p = tap<K - 1>(r, bc, tid);
        t1 = make_float4(p.w, rl.x, rl.y, rl.z);
        t2 = make_float4(p.z, p.w, rl.x, rl.y);
        t3 = make_float4(p.y, p.z, p.w, rl.x);
    } else if constexpr (d == 2) {
        const float4 p  = tap<K - 1>(r, bc, tid);
        const float4 p2 = tap<K - 2>(r, bc, tid);
        t1 = make_float4(p.z, p.w, rl.x, rl.y);
        t2 = p;
        t3 = make_float4(p2.z, p2.w, p.x, p.y);
    } else {
        constexpr int D4 = d >> 2;              // dilation in whole groups
        t1 = tap<K -     D4>(r, bc, tid);
        t2 = tap<K - 2 * D4>(r, bc, tid);
        t3 = tap<K - 3 * D4>(r, bc, tid);
    }

    acc.x += G1.w * rl.x + G1.z * t1.x + G1.y * t2.x + G1.x * t3.x;
    acc.y += G1.w * rl.y + G1.z * t1.y + G1.y * t2.y + G1.x * t3.y;
    acc.z += G1.w * rl.z + G1.z * t1.z + G1.y * t2.z + G1.x * t3.z;
    acc.w += G1.w * rl.w + G1.z * t1.w + G1.y * t2.w + G1.x * t3.w;

    if constexpr (LEV != MR_DEPTH - 1) {
        float4 nl;
        nl.x = F0.w * rl.x + F0.z * t1.x + F0.y * t2.x + F0.x * t3.x;
        nl.y = F0.w * rl.y + F0.z * t1.y + F0.y * t2.y + F0.x * t3.y;
        nl.z = F0.w * rl.z + F0.z * t1.z + F0.y * t2.z + F0.x * t3.z;
        nl.w = F0.w * rl.w + F0.z * t1.w + F0.y * t2.w + F0.x * t3.w;
        rset<K>(r, nl);
        bn[(K << 8) + tid] = nl;   // consecutive slots across lanes: conflict-free
    }
}

__global__ __launch_bounds__(TPB) void multires_fused(
    const float* __restrict__ x,
    const float* __restrict__ h0,
    const float* __restrict__ h1,
    const float* __restrict__ w,
    float* __restrict__ out)
{
    __shared__ float4 bufA[NG];
    __shared__ float4 bufB[NG];   // 64 KiB total -> 2 blocks/CU

    const int row = blockIdx.x;            // b*C + c
    const int c   = row & (MR_C - 1);
    const int tid = threadIdx.x;

    // block-uniform filter/weight loads -> scalar regs
    const float4 F0 = ((const float4*)h0)[c];
    const float4 F1 = ((const float4*)h1)[c];
    const float* __restrict__ wrow = w + c * (MR_DEPTH + 2);
    const float wlast = wrow[MR_DEPTH + 1];
    const float w0    = wrow[0];

    const float4* __restrict__ xrow = (const float4*)(x + (size_t)row * MR_L);

    // slot base for the strided (coalesced-global) <-> transposed-LDS bounce
    const int sbase = ((tid & 7) << 8) + (tid >> 3);

    // prologue: coalesced global loads, scatter into transposed LDS layout
#pragma unroll
    for (int k = 0; k < 8; ++k)
        bufA[sbase + k * 32] = xrow[tid + (k << 8)];
    __syncthreads();

    // own contiguous run -> named res members + named accumulators
    Res8 r;
    float4 a0, a1, a2, a3, a4, a5, a6, a7;
#define INITK(K, A, RM) { const float4 t = bufA[((K) << 8) + tid]; r.RM = t;    \
        A = make_float4(wlast * t.x, wlast * t.y, wlast * t.z, wlast * t.w); }
    INITK(0, a0, r0) INITK(1, a1, r1) INITK(2, a2, r2) INITK(3, a3, r3)
    INITK(4, a4, r4) INITK(5, a5, r5) INITK(6, a6, r6) INITK(7, a7, r7)
#undef INITK

    const float4* bc = bufA;
    float4*       bn = bufB;

    // DESCENDING K: when group K is processed, members E<K still hold the
    // previous level's values -> register taps are correct.
#define LEVEL_BODY(LEV, GV)                                                     \
    gstep<LEV, 7>(r, a7, bc, bn, tid, F0, GV);                                  \
    gstep<LEV, 6>(r, a6, bc, bn, tid, F0, GV);                                  \
    gstep<LEV, 5>(r, a5, bc, bn, tid, F0, GV);                                  \
    gstep<LEV, 4>(r, a4, bc, bn, tid, F0, GV);                                  \
    gstep<LEV, 3>(r, a3, bc, bn, tid, F0, GV);                                  \
    gstep<LEV, 2>(r, a2, bc, bn, tid, F0, GV);                                  \
    gstep<LEV, 1>(r, a1, bc, bn, tid, F0, GV);                                  \
    gstep<LEV, 0>(r, a0, bc, bn, tid, F0, GV);

    // Levels 0..10: G1 = wi*F1; barrier + buffer swap after each.
#define DO_LEVEL(LEV)                                                           \
    {                                                                           \
        const float wi = wrow[MR_DEPTH - (LEV)];                                \
        const float4 G1 = make_float4(wi * F1.x, wi * F1.y, wi * F1.z, wi * F1.w); \
        LEVEL_BODY(LEV, G1)                                                     \
        __syncthreads();                                                        \
        const float4* t_ = bc; bc = bn; bn = (float4*)t_;                       \
    }

    DO_LEVEL(0)  DO_LEVEL(1)  DO_LEVEL(2)  DO_LEVEL(3)
    DO_LEVEL(4)  DO_LEVEL(5)  DO_LEVEL(6)  DO_LEVEL(7)
    DO_LEVEL(8)  DO_LEVEL(9)  DO_LEVEL(10)
#undef DO_LEVEL

    // Level 11 (last): fold w0*F0 into the accumulation coefficient:
    // acc += (w1*F1 + w0*F0) . taps  ==  w1*res_hi + w0*res_lo_final.
    // No nl, no LDS write, no barrier needed before the epilogue (epilogue
    // writes bn which level 11 never reads; level-10 bn reads were fenced
    // by the barrier after level 10).
    {
        const float w1 = wrow[1];
        const float4 GX = make_float4(w1 * F1.x + w0 * F0.x,
                                      w1 * F1.y + w0 * F0.y,
                                      w1 * F1.z + w0 * F0.z,
                                      w1 * F1.w + w0 * F0.w);
        LEVEL_BODY(11, GX)
    }
#undef LEVEL_BODY

    // epilogue: exact-erf GELU on named accs -> transposed LDS -> coalesced store
    const float inv_sqrt2 = 0.70710678118654752f;
#define EPI(K, A) {                                                             \
        float4 vv; float u;                                                     \
        u = A.x; vv.x = 0.5f * u * (1.0f + erff(u * inv_sqrt2));                \
        u = A.y; vv.y = 0.5f * u * (1.0f + erff(u * inv_sqrt2));                \
        u = A.z; vv.z = 0.5f * u * (1.0f + erff(u * inv_sqrt2));                \
        u = A.w; vv.w = 0.5f * u * (1.0f + erff(u * inv_sqrt2));                \
        bn[((K) << 8) + tid] = vv; }
    EPI(0, a0) EPI(1, a1) EPI(2, a2) EPI(3, a3)
    EPI(4, a4) EPI(5, a5) EPI(6, a6) EPI(7, a7)
#undef EPI
    __syncthreads();

    float4* __restrict__ orow = (float4*)(out + (size_t)row * MR_L);
#pragma unroll
    for (int k = 0; k < 8; ++k)
        orow[tid + (k << 8)] = bn[sbase + k * 32];
}

extern "C" void kernel_launch(void* const* d_in, const int* in_sizes, int n_in,
                              void* d_out, int out_size, void* d_ws, size_t ws_size,
                              hipStream_t stream) {
    const float* x  = (const float*)d_in[0];
    const float* h0 = (const float*)d_in[1];
    const float* h1 = (const float*)d_in[2];
    const float* w  = (const float*)d_in[3];
    float* o        = (float*)d_out;

    const int rows = in_sizes[0] / MR_L;   // B*C = 4096
    multires_fused<<<rows, TPB, 0, stream>>>(x, h0, h1, w, o);
}